// Round 4
// baseline (310.190 us; speedup 1.0000x reference)
//
#include <hip/hip_runtime.h>

#define BS        64
#define W_TOTAL_C 2234368
#define B_TOTAL_C 3526

__device__ __forceinline__ float silu_f(float v) {
    return v / (1.f + __expf(-v));
}

// ---------------------------------------------------------------------------
// One layer, split-K, no cross-block sync (kernel boundaries order layers):
//  - stage h-chunk into LDS; if PNK>0 h is rebuilt as
//    silu( sum_{k<PNK} prev_part[k][b][i] + prev_bias[i] )
//  - K-loop: a[0..VEC) += sh[i] * W[b][k0+i][o..o+VEC)   (float4/float2 loads)
//  - FINAL: tanh(a + bias) -> d_out ; else raw partial -> this layer's slice
template<int DIN, int DOUT, int KC, int NK, int PNK, int VEC, int BLK,
         bool FINAL, int WOFF, int PBOFF, int FBOFF>
__global__ __launch_bounds__(BLK)
void layer_kernel(const float* __restrict__ hin,   // x (PNK==0) or prev partials
                  const float* __restrict__ wbase,
                  const float* __restrict__ bias,
                  float* __restrict__ outp)        // partials slice, or d_out
{
    __shared__ float sh[KC];

    const int b   = blockIdx.z;
    const int ky  = blockIdx.y;
    const int k0  = ky * KC;
    const int tid = threadIdx.x;

    // ---- stage h chunk (fused prev-layer reduce + bias + silu) ----
    for (int i = tid; i < KC; i += BLK) {
        float s;
        if (PNK == 0) {
            s = hin[b * DIN + k0 + i];
        } else {
            s = bias[b * B_TOTAL_C + PBOFF + k0 + i];
            #pragma unroll
            for (int k = 0; k < PNK; ++k)
                s += hin[((size_t)k * BS + b) * DIN + k0 + i];
            s = silu_f(s);
        }
        sh[i] = s;
    }
    __syncthreads();

    const int o = (blockIdx.x * BLK + tid) * VEC;

    float a[VEC];
    #pragma unroll
    for (int j = 0; j < VEC; ++j) a[j] = 0.f;

    const float* wp = wbase + (size_t)b * W_TOTAL_C + WOFF
                            + (size_t)k0 * DOUT + o;

    if (o + VEC <= DOUT) {
        // full vector path
        #pragma unroll 8
        for (int i = 0; i < KC; ++i) {
            const float hv = sh[i];
            if (VEC == 4) {
                const float4 w = *reinterpret_cast<const float4*>(wp);
                a[0] = fmaf(hv, w.x, a[0]);
                a[1] = fmaf(hv, w.y, a[1]);
                a[2] = fmaf(hv, w.z, a[2]);
                a[3] = fmaf(hv, w.w, a[3]);
            } else {
                const float2 w = *reinterpret_cast<const float2*>(wp);
                a[0] = fmaf(hv, w.x, a[0]);
                a[1] = fmaf(hv, w.y, a[1]);
            }
            wp += DOUT;
        }
    } else if (o < DOUT) {
        // scalar edge path (only the dout=1862 tail block)
        const int rem = DOUT - o;
        for (int i = 0; i < KC; ++i) {
            const float hv = sh[i];
            for (int j = 0; j < rem; ++j)
                a[j] = fmaf(hv, wp[j], a[j]);
            wp += DOUT;
        }
    } else {
        return;
    }

    if (FINAL) {
        #pragma unroll
        for (int j = 0; j < VEC; ++j) {
            if (o + j < DOUT) {
                float v = a[j] + bias[b * B_TOTAL_C + FBOFF + o + j];
                outp[b * DOUT + o + j] = tanhf(v);
            }
        }
    } else {
        float* pp = outp + ((size_t)ky * BS + b) * DOUT + o;
        if (VEC == 4) *reinterpret_cast<float4*>(pp) = make_float4(a[0], a[1], a[2], a[3]);
        else          *reinterpret_cast<float2*>(pp) = make_float2(a[0], a[1]);
    }
}

// ---------------------------------------------------------------------------
extern "C" void kernel_launch(void* const* d_in, const int* in_sizes, int n_in,
                              void* d_out, int out_size, void* d_ws, size_t ws_size,
                              hipStream_t stream)
{
    const float* x    = (const float*)d_in[0];   // [64][1862]
    const float* wts  = (const float*)d_in[1];   // [64][W_TOTAL]
    const float* bias = (const float*)d_in[2];   // [64][B_TOTAL]
    float* out = (float*)d_out;                  // [64][1862]

    // partial slices (floats); every slot written before read within one call
    float* p0 = (float*)d_ws;        // 14*64*512 = 458752
    float* p1 = p0 + 458752;         //  8*64*256 = 131072
    float* p2 = p1 + 131072;         //  8*64*128 =  65536
    float* p3 = p2 + 65536;          //  4*64*256 =  65536
    float* p4 = p3 + 65536;          //  8*64*512 = 262144   (total ~3.93 MB)

    // L0: 1862 -> 512   x -> p0         grid 1x14x64 = 896 blk (BLK=64,VEC=4)
    layer_kernel<1862, 512, 133, 14, 0, 4, 64, false,       0,    0,    0>
        <<<dim3(2, 14, BS), 64, 0, stream>>>(x, wts, bias, p0);
    // L1: 512 -> 256    p0 -> p1        grid 1x8x64 (BLK=64,VEC=4)
    layer_kernel< 512, 256,  64,  8, 14, 4, 64, false,  953344,    0,    0>
        <<<dim3(1, 8, BS), 64, 0, stream>>>(p0, wts, bias, p1);
    // L2: 256 -> 128    p1 -> p2        grid 1x8x64 (BLK=64,VEC=2)
    layer_kernel< 256, 128,  32,  8,  8, 2, 64, false, 1084416,  512,    0>
        <<<dim3(1, 8, BS), 64, 0, stream>>>(p1, wts, bias, p2);
    // L3: 128 -> 256    p2 -> p3        grid 1x4x64 (BLK=64,VEC=4)
    layer_kernel< 128, 256,  32,  4,  8, 4, 64, false, 1117184,  768,    0>
        <<<dim3(1, 4, BS), 64, 0, stream>>>(p2, wts, bias, p3);
    // L4: 256 -> 512    p3 -> p4        grid 1x8x64 (BLK=128,VEC=4)
    layer_kernel< 256, 512,  32,  8,  4, 4, 128, false, 1149952,  896,    0>
        <<<dim3(1, 8, BS), 128, 0, stream>>>(p3, wts, bias, p4);
    // L5: 512 -> 1862   p4 -> out       split-O, full K; grid 8x1x64 (BLK=64,VEC=4)
    layer_kernel< 512, 1862, 512, 1,  8, 4, 64, true, 1281024, 1152, 1664>
        <<<dim3(8, 1, BS), 64, 0, stream>>>(p4, wts, bias, out);
}

// Round 5
// 160.755 us; speedup vs baseline: 1.9296x; 1.9296x over previous
//
#include <hip/hip_runtime.h>

#define BS        64
#define W_TOTAL_C 2234368
#define B_TOTAL_C 3526

__device__ __forceinline__ float silu_f(float v) {
    return v / (1.f + __expf(-v));
}

// ---------------------------------------------------------------------------
// One layer, split-K, no cross-block sync (kernel boundaries order layers):
//  - stage h-chunk into LDS; if PNK>0 h is rebuilt as
//    silu( sum_{k<PNK} prev_part[k][b][i] + prev_bias[i] )
//  - K-loop: a[0..VEC) += sh[i] * W[b][k0+i][o..o+VEC)  (float4/float2 loads)
//  - FINAL: tanh(a + bias) -> d_out ; else raw partial -> this layer's slice
// NOTE: no runtime-indexed register arrays anywhere (rule #20) — the DOUT
// tail (only L5, rem==2) is a dedicated static float2 branch.
template<int DIN, int DOUT, int KC, int NK, int PNK, int VEC, int BLK,
         bool FINAL, int WOFF, int PBOFF, int FBOFF>
__global__ __launch_bounds__(BLK)
void layer_kernel(const float* __restrict__ hin,   // x (PNK==0) or prev partials
                  const float* __restrict__ wbase,
                  const float* __restrict__ bias,
                  float* __restrict__ outp)        // partials slice, or d_out
{
    __shared__ float sh[KC];

    const int b   = blockIdx.z;
    const int ky  = blockIdx.y;
    const int k0  = ky * KC;
    const int tid = threadIdx.x;

    // ---- stage h chunk (fused prev-layer reduce + bias + silu) ----
    for (int i = tid; i < KC; i += BLK) {
        float s;
        if (PNK == 0) {
            s = hin[b * DIN + k0 + i];
        } else {
            s = bias[b * B_TOTAL_C + PBOFF + k0 + i];
            #pragma unroll
            for (int k = 0; k < PNK; ++k)
                s += hin[((size_t)k * BS + b) * DIN + k0 + i];
            s = silu_f(s);
        }
        sh[i] = s;
    }
    __syncthreads();

    const int o = (blockIdx.x * BLK + tid) * VEC;

    float a0 = 0.f, a1 = 0.f, a2 = 0.f, a3 = 0.f;

    const float* wp = wbase + (size_t)b * W_TOTAL_C + WOFF
                            + (size_t)k0 * DOUT + o;

    if (o + VEC <= DOUT) {
        // full vector path (exact-coverage layers always take this)
        #pragma unroll 8
        for (int i = 0; i < KC; ++i) {
            const float hv = sh[i];
            if (VEC == 4) {
                const float4 w = *reinterpret_cast<const float4*>(wp);
                a0 = fmaf(hv, w.x, a0);
                a1 = fmaf(hv, w.y, a1);
                a2 = fmaf(hv, w.z, a2);
                a3 = fmaf(hv, w.w, a3);
            } else {
                const float2 w = *reinterpret_cast<const float2*>(wp);
                a0 = fmaf(hv, w.x, a0);
                a1 = fmaf(hv, w.y, a1);
            }
            wp += DOUT;
        }
    } else if (VEC == 4 && o + 2 <= DOUT) {
        // static two-element tail (L5: o == 1860, rem == 2)
        #pragma unroll 8
        for (int i = 0; i < KC; ++i) {
            const float hv = sh[i];
            const float2 w = *reinterpret_cast<const float2*>(wp);
            a0 = fmaf(hv, w.x, a0);
            a1 = fmaf(hv, w.y, a1);
            wp += DOUT;
        }
    } else if (o < DOUT) {
        // static single-element tail (unused for even DOUT; kept static)
        for (int i = 0; i < KC; ++i) {
            a0 = fmaf(sh[i], wp[0], a0);
            wp += DOUT;
        }
    } else {
        return;
    }

    if (FINAL) {
        // statically-indexed, predicated stores
        if (o + 0 < DOUT)
            outp[b * DOUT + o + 0] = tanhf(a0 + bias[b * B_TOTAL_C + FBOFF + o + 0]);
        if (o + 1 < DOUT)
            outp[b * DOUT + o + 1] = tanhf(a1 + bias[b * B_TOTAL_C + FBOFF + o + 1]);
        if (VEC == 4) {
            if (o + 2 < DOUT)
                outp[b * DOUT + o + 2] = tanhf(a2 + bias[b * B_TOTAL_C + FBOFF + o + 2]);
            if (o + 3 < DOUT)
                outp[b * DOUT + o + 3] = tanhf(a3 + bias[b * B_TOTAL_C + FBOFF + o + 3]);
        }
    } else {
        // non-final layers have exact coverage: unconditional vector store
        float* pp = outp + ((size_t)ky * BS + b) * DOUT + o;
        if (VEC == 4) *reinterpret_cast<float4*>(pp) = make_float4(a0, a1, a2, a3);
        else          *reinterpret_cast<float2*>(pp) = make_float2(a0, a1);
    }
}

// ---------------------------------------------------------------------------
extern "C" void kernel_launch(void* const* d_in, const int* in_sizes, int n_in,
                              void* d_out, int out_size, void* d_ws, size_t ws_size,
                              hipStream_t stream)
{
    const float* x    = (const float*)d_in[0];   // [64][1862]
    const float* wts  = (const float*)d_in[1];   // [64][W_TOTAL]
    const float* bias = (const float*)d_in[2];   // [64][B_TOTAL]
    float* out = (float*)d_out;                  // [64][1862]

    // partial slices (floats); every slot written before read within one call
    float* p0 = (float*)d_ws;        // 14*64*512 = 458752
    float* p1 = p0 + 458752;         //  8*64*256 = 131072
    float* p2 = p1 + 131072;         //  8*64*128 =  65536
    float* p3 = p2 + 65536;          //  4*64*256 =  65536
    float* p4 = p3 + 65536;          //  8*64*512 = 262144   (~3.93 MB total)

    // L0: 1862 -> 512   x -> p0     grid 2x14x64 = 1792 waves (BLK=64,VEC=4)
    layer_kernel<1862, 512, 133, 14, 0, 4, 64, false,       0,    0,    0>
        <<<dim3(2, 14, BS), 64, 0, stream>>>(x, wts, bias, p0);
    // L1: 512 -> 256    p0 -> p1    grid 1x8x64 (BLK=64,VEC=4)
    layer_kernel< 512, 256,  64,  8, 14, 4, 64, false,  953344,    0,    0>
        <<<dim3(1, 8, BS), 64, 0, stream>>>(p0, wts, bias, p1);
    // L2: 256 -> 128    p1 -> p2    grid 1x8x64 (BLK=64,VEC=2)
    layer_kernel< 256, 128,  32,  8,  8, 2, 64, false, 1084416,  512,    0>
        <<<dim3(1, 8, BS), 64, 0, stream>>>(p1, wts, bias, p2);
    // L3: 128 -> 256    p2 -> p3    grid 1x4x64 (BLK=64,VEC=4)
    layer_kernel< 128, 256,  32,  4,  8, 4, 64, false, 1117184,  768,    0>
        <<<dim3(1, 4, BS), 64, 0, stream>>>(p2, wts, bias, p3);
    // L4: 256 -> 512    p3 -> p4    grid 1x8x64 (BLK=128,VEC=4)
    layer_kernel< 256, 512,  32,  8,  4, 4, 128, false, 1149952,  896,    0>
        <<<dim3(1, 8, BS), 128, 0, stream>>>(p3, wts, bias, p4);
    // L5: 512 -> 1862   p4 -> out   split-O full-K; grid 8x1x64 (BLK=64,VEC=4)
    layer_kernel< 512, 1862, 512, 1,  8, 4, 64, true, 1281024, 1152, 1664>
        <<<dim3(8, 1, BS), 64, 0, stream>>>(p4, wts, bias, out);
}

// Round 6
// 137.745 us; speedup vs baseline: 2.2519x; 1.1671x over previous
//
#include <hip/hip_runtime.h>

#define BS        64
#define W_TOTAL_C 2234368
#define B_TOTAL_C 3526

__device__ __forceinline__ float silu_f(float v) {
    return v / (1.f + __expf(-v));
}

// ---------------------------------------------------------------------------
// One layer, split-K, no cross-block sync (kernel boundaries order layers):
//  - stage h-chunk into LDS; if PNK>0 h is rebuilt as
//    silu( sum_{k<PNK} prev_part[k][b][i] + prev_bias[i] )
//  - K-loop: a[0..VEC) += sh[i] * W[b][k0+i][o..o+VEC)  (float4/float2 loads)
//  - FINAL: tanh(a + bias) -> d_out ; else raw partial -> this layer's slice
// VEC=4 ONLY on layers whose DOUT*4 is a multiple of 16 (alignment!).
// No runtime-indexed register arrays (rule #20): scalars a0..a3, static tails.
template<int DIN, int DOUT, int KC, int NK, int PNK, int VEC, int BLK,
         bool FINAL, int WOFF, int PBOFF, int FBOFF>
__global__ __launch_bounds__(BLK)
void layer_kernel(const float* __restrict__ hin,   // x (PNK==0) or prev partials
                  const float* __restrict__ wbase,
                  const float* __restrict__ bias,
                  float* __restrict__ outp)        // partials slice, or d_out
{
    __shared__ float sh[KC];

    const int b   = blockIdx.z;
    const int ky  = blockIdx.y;
    const int k0  = ky * KC;
    const int tid = threadIdx.x;

    // ---- stage h chunk (fused prev-layer reduce + bias + silu) ----
    for (int i = tid; i < KC; i += BLK) {
        float s;
        if (PNK == 0) {
            s = hin[b * DIN + k0 + i];
        } else {
            s = bias[b * B_TOTAL_C + PBOFF + k0 + i];
            #pragma unroll
            for (int k = 0; k < PNK; ++k)
                s += hin[((size_t)k * BS + b) * DIN + k0 + i];
            s = silu_f(s);
        }
        sh[i] = s;
    }
    __syncthreads();

    const int o = (blockIdx.x * BLK + tid) * VEC;

    float a0 = 0.f, a1 = 0.f, a2 = 0.f, a3 = 0.f;

    const float* wp = wbase + (size_t)b * W_TOTAL_C + WOFF
                            + (size_t)k0 * DOUT + o;

    if (o + VEC <= DOUT) {
        // full vector path (exact-coverage layers always take this)
        #pragma unroll 8
        for (int i = 0; i < KC; ++i) {
            const float hv = sh[i];
            if (VEC == 4) {
                const float4 w = *reinterpret_cast<const float4*>(wp);
                a0 = fmaf(hv, w.x, a0);
                a1 = fmaf(hv, w.y, a1);
                a2 = fmaf(hv, w.z, a2);
                a3 = fmaf(hv, w.w, a3);
            } else {
                const float2 w = *reinterpret_cast<const float2*>(wp);
                a0 = fmaf(hv, w.x, a0);
                a1 = fmaf(hv, w.y, a1);
            }
            wp += DOUT;
        }
    } else if (o < DOUT) {
        // static single-element tail (never taken with current configs:
        // all layers have exact coverage or even-DOUT float2 coverage)
        for (int i = 0; i < KC; ++i) {
            a0 = fmaf(sh[i], wp[0], a0);
            wp += DOUT;
        }
    } else {
        return;
    }

    if (FINAL) {
        if (o + 0 < DOUT)
            outp[b * DOUT + o + 0] = tanhf(a0 + bias[b * B_TOTAL_C + FBOFF + o + 0]);
        if (o + 1 < DOUT)
            outp[b * DOUT + o + 1] = tanhf(a1 + bias[b * B_TOTAL_C + FBOFF + o + 1]);
        if (VEC == 4) {
            if (o + 2 < DOUT)
                outp[b * DOUT + o + 2] = tanhf(a2 + bias[b * B_TOTAL_C + FBOFF + o + 2]);
            if (o + 3 < DOUT)
                outp[b * DOUT + o + 3] = tanhf(a3 + bias[b * B_TOTAL_C + FBOFF + o + 3]);
        }
    } else {
        // non-final layers have exact coverage: unconditional vector store
        float* pp = outp + ((size_t)ky * BS + b) * DOUT + o;
        if (VEC == 4) *reinterpret_cast<float4*>(pp) = make_float4(a0, a1, a2, a3);
        else          *reinterpret_cast<float2*>(pp) = make_float2(a0, a1);
    }
}

// ---------------------------------------------------------------------------
extern "C" void kernel_launch(void* const* d_in, const int* in_sizes, int n_in,
                              void* d_out, int out_size, void* d_ws, size_t ws_size,
                              hipStream_t stream)
{
    const float* x    = (const float*)d_in[0];   // [64][1862]
    const float* wts  = (const float*)d_in[1];   // [64][W_TOTAL]
    const float* bias = (const float*)d_in[2];   // [64][B_TOTAL]
    float* out = (float*)d_out;                  // [64][1862]

    // partial slices (floats); every slot written before read within one call
    float* p0 = (float*)d_ws;        // 14*64*512 = 458752
    float* p1 = p0 + 458752;         //  4*64*256 =  65536
    float* p2 = p1 + 65536;          //  4*64*128 =  32768
    float* p3 = p2 + 32768;          //  4*64*256 =  65536
    float* p4 = p3 + 65536;          //  4*64*512 = 131072   (~2.9 MB total)

    // L0: 1862 -> 512  x -> p0    aligned VEC=4; grid 1x14x64 = 896 blk,
    //     1792 waves (7/CU); exact coverage 1*128*4 = 512
    layer_kernel<1862, 512, 133, 14, 0, 4, 128, false,       0,    0,    0>
        <<<dim3(1, 14, BS), 128, 0, stream>>>(x, wts, bias, p0);
    // L1: 512 -> 256   p0 -> p1   aligned VEC=4; exact 1*64*4 = 256
    layer_kernel< 512, 256, 128,  4, 14, 4, 64, false,  953344,    0,    0>
        <<<dim3(1, 4, BS), 64, 0, stream>>>(p0, wts, bias, p1);
    // L2: 256 -> 128   p1 -> p2   VEC=2; exact 1*64*2 = 128
    layer_kernel< 256, 128,  64,  4,  4, 2, 64, false, 1084416,  512,    0>
        <<<dim3(1, 4, BS), 64, 0, stream>>>(p1, wts, bias, p2);
    // L3: 128 -> 256   p2 -> p3   aligned VEC=4; exact 1*64*4 = 256
    layer_kernel< 128, 256,  32,  4,  4, 4, 64, false, 1117184,  768,    0>
        <<<dim3(1, 4, BS), 64, 0, stream>>>(p2, wts, bias, p3);
    // L4: 256 -> 512   p3 -> p4   aligned VEC=4; exact 1*128*4 = 512
    layer_kernel< 256, 512,  64,  4,  4, 4, 128, false, 1149952,  896,    0>
        <<<dim3(1, 4, BS), 128, 0, stream>>>(p3, wts, bias, p4);
    // L5: 512 -> 1862  p4 -> out  VEC=2 (odd-row stride => keep 8B aligned);
    //     split-O full-K; grid 8x1x64 = 512 blk (1024 waves)
    layer_kernel< 512, 1862, 512, 1,  4, 2, 128, true, 1281024, 1152, 1664>
        <<<dim3(8, 1, BS), 128, 0, stream>>>(p4, wts, bias, out);
}

// Round 7
// 134.161 us; speedup vs baseline: 2.3121x; 1.0267x over previous
//
#include <hip/hip_runtime.h>

#define BS        64
#define W_TOTAL_C 2234368
#define B_TOTAL_C 3526

__device__ __forceinline__ float silu_f(float v) {
    return v / (1.f + __expf(-v));
}

// ---------------------------------------------------------------------------
// One layer, split-K, no cross-block sync (kernel boundaries order layers):
//  - stage h-chunk into LDS; if PNK>0 h is rebuilt as
//    silu( sum_{k<PNK} prev_part[k][b][i] + prev_bias[i] )
//  - K-loop: a[0..VEC) += sh[i] * W[b][k0+i][o..o+VEC)  (float2 loads: 8B/lane,
//    always aligned for even DOUT; wave count carries the BW)
//  - FINAL: tanh(a + bias) -> d_out ; else raw partial -> this layer's slice
// No runtime-indexed register arrays (rule #20): scalar accumulators only.
template<int DIN, int DOUT, int KC, int NK, int PNK, int VEC, int BLK,
         bool FINAL, int WOFF, int PBOFF, int FBOFF>
__global__ __launch_bounds__(BLK)
void layer_kernel(const float* __restrict__ hin,   // x (PNK==0) or prev partials
                  const float* __restrict__ wbase,
                  const float* __restrict__ bias,
                  float* __restrict__ outp)        // partials slice, or d_out
{
    __shared__ float sh[KC];

    const int b   = blockIdx.z;
    const int ky  = blockIdx.y;
    const int k0  = ky * KC;
    const int tid = threadIdx.x;

    // ---- stage h chunk (fused prev-layer reduce + bias + silu) ----
    for (int i = tid; i < KC; i += BLK) {
        float s;
        if (PNK == 0) {
            s = hin[b * DIN + k0 + i];
        } else {
            s = bias[b * B_TOTAL_C + PBOFF + k0 + i];
            #pragma unroll
            for (int k = 0; k < PNK; ++k)
                s += hin[((size_t)k * BS + b) * DIN + k0 + i];
            s = silu_f(s);
        }
        sh[i] = s;
    }
    __syncthreads();

    const int o = (blockIdx.x * BLK + tid) * VEC;

    float a0 = 0.f, a1 = 0.f, a2 = 0.f, a3 = 0.f;

    const float* wp = wbase + (size_t)b * W_TOTAL_C + WOFF
                            + (size_t)k0 * DOUT + o;

    if (o + VEC <= DOUT) {
        #pragma unroll 8
        for (int i = 0; i < KC; ++i) {
            const float hv = sh[i];
            if (VEC == 4) {
                const float4 w = *reinterpret_cast<const float4*>(wp);
                a0 = fmaf(hv, w.x, a0);
                a1 = fmaf(hv, w.y, a1);
                a2 = fmaf(hv, w.z, a2);
                a3 = fmaf(hv, w.w, a3);
            } else {
                const float2 w = *reinterpret_cast<const float2*>(wp);
                a0 = fmaf(hv, w.x, a0);
                a1 = fmaf(hv, w.y, a1);
            }
            wp += DOUT;
        }
    } else if (o < DOUT) {
        // static single-element tail (never taken with current configs)
        for (int i = 0; i < KC; ++i) {
            a0 = fmaf(sh[i], wp[0], a0);
            wp += DOUT;
        }
    } else {
        return;
    }

    if (FINAL) {
        if (o + 0 < DOUT)
            outp[b * DOUT + o + 0] = tanhf(a0 + bias[b * B_TOTAL_C + FBOFF + o + 0]);
        if (o + 1 < DOUT)
            outp[b * DOUT + o + 1] = tanhf(a1 + bias[b * B_TOTAL_C + FBOFF + o + 1]);
        if (VEC == 4) {
            if (o + 2 < DOUT)
                outp[b * DOUT + o + 2] = tanhf(a2 + bias[b * B_TOTAL_C + FBOFF + o + 2]);
            if (o + 3 < DOUT)
                outp[b * DOUT + o + 3] = tanhf(a3 + bias[b * B_TOTAL_C + FBOFF + o + 3]);
        }
    } else {
        float* pp = outp + ((size_t)ky * BS + b) * DOUT + o;
        if (VEC == 4) *reinterpret_cast<float4*>(pp) = make_float4(a0, a1, a2, a3);
        else          *reinterpret_cast<float2*>(pp) = make_float2(a0, a1);
    }
}

// ---------------------------------------------------------------------------
extern "C" void kernel_launch(void* const* d_in, const int* in_sizes, int n_in,
                              void* d_out, int out_size, void* d_ws, size_t ws_size,
                              hipStream_t stream)
{
    const float* x    = (const float*)d_in[0];   // [64][1862]
    const float* wts  = (const float*)d_in[1];   // [64][W_TOTAL]
    const float* bias = (const float*)d_in[2];   // [64][B_TOTAL]
    float* out = (float*)d_out;                  // [64][1862]

    // partial slices (floats); every slot written before read within one call
    float* p0 = (float*)d_ws;        //  7*64*512 = 229376
    float* p1 = p0 + 229376;         // 16*64*256 = 262144
    float* p2 = p1 + 262144;         // 16*64*128 = 131072
    float* p3 = p2 + 131072;         //  8*64*256 = 131072
    float* p4 = p3 + 131072;         //  8*64*512 = 262144   (~4.06 MB total)

    // L0: 1862 -> 512  x -> p0   EXACT R3 config: 896 blk x 2 waves, float2
    layer_kernel<1862, 512, 266,  7,  0, 2, 128, false,       0,    0,    0>
        <<<dim3(2, 7, BS), 128, 0, stream>>>(x, wts, bias, p0);
    // L1: 512 -> 256   p0 -> p1   2048 blk x 1 wave (8 waves/CU), float2
    layer_kernel< 512, 256,  32, 16,  7, 2, 64, false,  953344,    0,    0>
        <<<dim3(2, 16, BS), 64, 0, stream>>>(p0, wts, bias, p1);
    // L2: 256 -> 128   p1 -> p2   1024 blk x 1 wave, float2
    layer_kernel< 256, 128,  16, 16, 16, 2, 64, false, 1084416,  512,    0>
        <<<dim3(1, 16, BS), 64, 0, stream>>>(p1, wts, bias, p2);
    // L3: 128 -> 256   p2 -> p3   1024 blk x 1 wave, float2
    layer_kernel< 128, 256,  16,  8, 16, 2, 64, false, 1117184,  768,    0>
        <<<dim3(2, 8, BS), 64, 0, stream>>>(p2, wts, bias, p3);
    // L4: 256 -> 512   p3 -> p4   2048 blk x 1 wave, float2
    layer_kernel< 256, 512,  32,  8,  8, 2, 64, false, 1149952,  896,    0>
        <<<dim3(4, 8, BS), 64, 0, stream>>>(p3, wts, bias, p4);
    // L5: 512 -> 1862  p4 -> out  EXACT R3 config: 512 blk x 2 waves, float2
    layer_kernel< 512, 1862, 512,  1,  8, 2, 128, true, 1281024, 1152, 1664>
        <<<dim3(8, 1, BS), 128, 0, stream>>>(p4, wts, bias, out);
}